// Round 6
// baseline (2179.836 us; speedup 1.0000x reference)
//
#include <hip/hip_runtime.h>
#include <cstdint>

// ---------------- problem constants ----------------
#define SEQ   386
#define NP1   385
#define HDIM  256
#define G4    1024
#define EMBD  128
#define LABV  128
#define OUTC  129   // 128 label + 1 split

typedef _Float16 h2 __attribute__((ext_vector_type(2)));
typedef _Float16 f16x8 __attribute__((ext_vector_type(8)));
typedef float    f32x4 __attribute__((ext_vector_type(4)));

__device__ __forceinline__ uint32_t pack2(float a, float b) {
    h2 v; v[0] = (_Float16)a; v[1] = (_Float16)b;
    return __builtin_bit_cast(uint32_t, v);
}

__device__ __forceinline__ float sigm(float x) { return 1.f / (1.f + __expf(-x)); }
__device__ __forceinline__ float ftanh(float x) {
    x = fminf(fmaxf(x, -15.f), 15.f);
    float e = __expf(2.f * x);
    return (e - 1.f) / (e + 1.f);
}

// 12 MFMAs: two row-tiles (C0,C1) x six K-slices, A operands pinned to AGPRs.
// Hazard discipline (the round-5 numerics bug): the compiler treats asm as
// complete at its end, but the trailing MFMAs are still READING their A/B
// sources for several passes after issue. Without exit padding it may schedule
// the next ds_read/VALU write into B registers inside that window ->
// deterministic corruption (absmax 6.5e-3). s_nop 3 at entry covers
// VALU-write(C zero-init) -> MFMA SrcC; s_nop 7 at exit covers in-flight
// source reads before any subsequent overwrite. XDL->XDL same-C chains inside
// need no waits.
__device__ __forceinline__ void mfma12(f32x4& C0, f32x4& C1,
                                       f16x8 A00, f16x8 A01, f16x8 A10, f16x8 A11,
                                       f16x8 A20, f16x8 A21, f16x8 A30, f16x8 A31,
                                       f16x8 A40, f16x8 A41, f16x8 A50, f16x8 A51,
                                       f16x8 B0, f16x8 B1, f16x8 B2,
                                       f16x8 B3, f16x8 B4, f16x8 B5) {
    asm("s_nop 3\n\t"
        "v_mfma_f32_16x16x32_f16 %0, %2, %14, %0\n\t"
        "v_mfma_f32_16x16x32_f16 %1, %3, %14, %1\n\t"
        "v_mfma_f32_16x16x32_f16 %0, %4, %15, %0\n\t"
        "v_mfma_f32_16x16x32_f16 %1, %5, %15, %1\n\t"
        "v_mfma_f32_16x16x32_f16 %0, %6, %16, %0\n\t"
        "v_mfma_f32_16x16x32_f16 %1, %7, %16, %1\n\t"
        "v_mfma_f32_16x16x32_f16 %0, %8, %17, %0\n\t"
        "v_mfma_f32_16x16x32_f16 %1, %9, %17, %1\n\t"
        "v_mfma_f32_16x16x32_f16 %0, %10, %18, %0\n\t"
        "v_mfma_f32_16x16x32_f16 %1, %11, %18, %1\n\t"
        "v_mfma_f32_16x16x32_f16 %0, %12, %19, %0\n\t"
        "v_mfma_f32_16x16x32_f16 %1, %13, %19, %1\n\t"
        "s_nop 7"
        : "+v"(C0), "+v"(C1)
        : "a"(A00), "a"(A01), "a"(A10), "a"(A11),
          "a"(A20), "a"(A21), "a"(A30), "a"(A31),
          "a"(A40), "a"(A41), "a"(A50), "a"(A51),
          "v"(B0), "v"(B1), "v"(B2), "v"(B3), "v"(B4), "v"(B5));
}

// ---------------- workspace layout (bytes) ----------------
#define OFF_EMB   0u                       // 386*128*4      = 197632
#define OFF_GX    197632u                  // 2*386*1024*4   = 3162112
#define OFF_WREG  3359744u                 // 2*384*64*16    = 786432 (MFMA A-frags kb0..5)
#define OFF_WLDS  4146176u                 // 2*128*64*16    = 262144 (MFMA A-frags kb6..7)
#define OFF_F     4408320u                 // 385*256*4      = 394240
#define OFF_B     4802560u                 // 385*256*4      = 394240
#define OFF_DL    5196800u                 // 385*256*4      = 394240
#define OFF_DS    5591040u                 // 385*256*4      = 394240
#define OFF_W2F   5985280u                 // 32*128*8*2     = 65536 (f16 B-fragments)
// total ~6.05 MB

// ---------------- K1: embedding gather ----------------
__global__ void k_embed(const int* __restrict__ tag_ids, const int* __restrict__ word_ids,
                        const float* __restrict__ tag_emb, const float* __restrict__ word_emb,
                        float* __restrict__ emb) {
    int t = blockIdx.x, d = threadIdx.x;
    emb[t * EMBD + d] = tag_emb[tag_ids[t] * EMBD + d] + word_emb[word_ids[t] * EMBD + d];
}

// ---------------- K2: Gx[dir][t][1024] = Wx @ emb[t] + b ----------------
__global__ __launch_bounds__(256) void k_gx(const float* __restrict__ emb,
                                            const float* __restrict__ wxf, const float* __restrict__ bf_,
                                            const float* __restrict__ wxb, const float* __restrict__ bb_,
                                            float* __restrict__ gx) {
    const int dir = blockIdx.y;
    const int t0  = blockIdx.x * 8;
    const float* Wx   = dir ? wxb : wxf;
    const float* bias = dir ? bb_ : bf_;
    __shared__ float se[8 * EMBD];
    for (int idx = threadIdx.x; idx < 8 * EMBD; idx += 256) {
        int tt = t0 + (idx >> 7);
        se[idx] = (tt < SEQ) ? emb[tt * EMBD + (idx & 127)] : 0.f;
    }
    __syncthreads();
    const float4* se4 = (const float4*)se;
    for (int q = 0; q < 4; ++q) {
        int r = threadIdx.x + q * 256;
        float bv = bias[r];
        float acc[8];
#pragma unroll
        for (int tt = 0; tt < 8; ++tt) acc[tt] = bv;
        const float4* wrow = (const float4*)(Wx + r * EMBD);
        for (int d4 = 0; d4 < 32; ++d4) {
            float4 w = wrow[d4];
#pragma unroll
            for (int tt = 0; tt < 8; ++tt) {
                float4 e = se4[tt * 32 + d4];
                acc[tt] += w.x * e.x + w.y * e.y + w.z * e.z + w.w * e.w;
            }
        }
        for (int tt = 0; tt < 8; ++tt) {
            int t = t0 + tt;
            if (t < SEQ) gx[(dir * SEQ + t) * G4 + r] = acc[tt];
        }
    }
}

// ---------------- K3: convert Wh fp32 -> f16 MFMA A-fragments ----------------
// Fragment (Tg, kb): lane l holds Wh[row = Tg*16 + (l&15)][col = kb*32 + (l>>4)*8 .. +7]
// kb 0..5 -> wreg[dir][(Tg*6+kb)*64 + lane]   (AGPR-resident in k_lstm)
// kb 6..7 -> wldsg[dir][(kb-6)*4096 + Tg*64 + lane]  (LDS-streamed in k_lstm)
__global__ void k_wconv(const float* __restrict__ whf, const float* __restrict__ whb,
                        uint4* __restrict__ wreg, uint4* __restrict__ wldsg) {
    const int dir = blockIdx.x;
    const float* Wh = dir ? whb : whf;
    int idx = blockIdx.y * 256 + threadIdx.x;   // [0, 32768)
    int lane = idx & 63;
    int fragid = idx >> 6;                      // 0..511
    int Tg = fragid >> 3, kb = fragid & 7;
    int r  = Tg * 16 + (lane & 15);
    int c0 = kb * 32 + (lane >> 4) * 8;
    const float* src = Wh + r * HDIM + c0;
    uint4 o;
    o.x = pack2(src[0], src[1]); o.y = pack2(src[2], src[3]);
    o.z = pack2(src[4], src[5]); o.w = pack2(src[6], src[7]);
    if (kb < 6) wreg [dir * 24576 + (Tg * 6 + kb) * 64 + lane] = o;
    else        wldsg[dir * 8192 + (kb - 6) * 4096 + Tg * 64 + lane] = o;
}

// ---------------- K4: the two LSTMs via MFMA + AGPR-pinned weights ----------------
// 1 block/dir, 512 threads = 8 waves = 2/SIMD -> 256 unified regs/wave.
// Weights kb0..5 (48 f16x8 = 192 regs/lane) are pinned to AGPRs via the "a"
// inline-asm constraint, so v_mfma consumes them IN PLACE (no per-use copy).
// kb6..7 stream from LDS (128 KiB). Wave owns 8 row-tiles, processed as 4
// quarters of 2 tiles (C=8 arch regs). Arch ~50-60 + 192 AGPR ~= 245 <= 256.
__global__ __launch_bounds__(512, 2)
void k_lstm(const uint4* __restrict__ wreg,
            const uint4* __restrict__ wldsg,
            const float* __restrict__ gx,
            float* __restrict__ fout, float* __restrict__ bout) {
    const int dir  = blockIdx.x;
    const int tid  = threadIdx.x;             // 0..511
    const int wave = tid >> 6;
    const int lane = tid & 63;
    const int q    = lane >> 4;               // 0..3
    const int c16  = lane & 15;

    __shared__ uint4    plane[8192];          // 131072 B: [kb2][Tg64][lane64]
    __shared__ float    gbuf[1024];           // 4096 B
    __shared__ __align__(16) _Float16 hbuf[2][256];   // 1024 B

    // stage the two LDS weight planes (kb 6,7)
    const uint4* wg = wldsg + dir * 8192;
    for (int i = tid; i < 8192; i += 512) plane[i] = wg[i];
    if (tid < 256) hbuf[0][tid] = (_Float16)0.f;

    // AGPR-resident A-fragments: wa[quarter][tile2][kb], kb 0..5
    f16x8 wa[4][2][6];
    const f16x8* wr = (const f16x8*)(wreg + dir * 24576);
#pragma unroll
    for (int qt = 0; qt < 4; ++qt)
#pragma unroll
        for (int t2 = 0; t2 < 2; ++t2)
#pragma unroll
            for (int kb = 0; kb < 6; ++kb)
                wa[qt][t2][kb] = wr[((wave * 8 + qt * 2 + t2) * 6 + kb) * 64 + lane];

    const float* gxd = gx + dir * SEQ * G4;
    float c = 0.f;
    float gxv[4], gn[4];
    const int tfirst = dir ? (SEQ - 1) : 0;
    if (tid < 256) {
#pragma unroll
        for (int g = 0; g < 4; ++g) gxv[g] = gxd[tfirst * G4 + g * 256 + tid];
    }
    __syncthreads();

    for (int s = 0; s < SEQ; ++s) {
        const int t = dir ? (SEQ - 1 - s) : s;
        // prefetch next step's gx early (hidden under the MFMA phase)
        if (tid < 256) {
            if (s < SEQ - 1) {
                int tn = dir ? (SEQ - 2 - s) : (s + 1);
#pragma unroll
                for (int g = 0; g < 4; ++g) gn[g] = gxd[tn * G4 + g * 256 + tid];
            } else {
#pragma unroll
                for (int g = 0; g < 4; ++g) gn[g] = 0.f;
            }
        }

        const f16x8* hb = (const f16x8*)hbuf[s & 1];   // index: kb*4 + q
#pragma unroll
        for (int qt = 0; qt < 4; ++qt) {
            const int Tg0 = wave * 8 + qt * 2;
            f32x4 C0 = {0.f, 0.f, 0.f, 0.f};
            f32x4 C1 = {0.f, 0.f, 0.f, 0.f};
            // LDS A-frags for kb6,7 (issued early; latency hides under the asm MFMAs)
            const uint4* pl = plane + Tg0 * 64 + lane;
            uint4 A60 = pl[0],    A61 = pl[64];
            uint4 A70 = pl[4096], A71 = pl[4160];
            // kb 0..5 (AGPR-resident) in one hazard-padded asm block
            f16x8 B0 = hb[0 * 4 + q], B1 = hb[1 * 4 + q], B2 = hb[2 * 4 + q];
            f16x8 B3 = hb[3 * 4 + q], B4 = hb[4 * 4 + q], B5 = hb[5 * 4 + q];
            mfma12(C0, C1,
                   wa[qt][0][0], wa[qt][1][0], wa[qt][0][1], wa[qt][1][1],
                   wa[qt][0][2], wa[qt][1][2], wa[qt][0][3], wa[qt][1][3],
                   wa[qt][0][4], wa[qt][1][4], wa[qt][0][5], wa[qt][1][5],
                   B0, B1, B2, B3, B4, B5);
            // kb 6..7 (LDS-streamed, intrinsics so C's consumers are compiler-managed)
            f16x8 B6 = hb[6 * 4 + q], B7 = hb[7 * 4 + q];
            C0 = __builtin_amdgcn_mfma_f32_16x16x32_f16(__builtin_bit_cast(f16x8, A60), B6, C0, 0, 0, 0);
            C1 = __builtin_amdgcn_mfma_f32_16x16x32_f16(__builtin_bit_cast(f16x8, A61), B6, C1, 0, 0, 0);
            C0 = __builtin_amdgcn_mfma_f32_16x16x32_f16(__builtin_bit_cast(f16x8, A70), B7, C0, 0, 0, 0);
            C1 = __builtin_amdgcn_mfma_f32_16x16x32_f16(__builtin_bit_cast(f16x8, A71), B7, C1, 0, 0, 0);
            // D cols are 16 identical copies; lanes c16==tile write rows q*4..q*4+3
            if (c16 == 0) *(f32x4*)&gbuf[(Tg0 + 0) * 16 + q * 4] = C0;
            if (c16 == 1) *(f32x4*)&gbuf[(Tg0 + 1) * 16 + q * 4] = C1;
        }
        __syncthreads();

        if (tid < 256) {
            float gi = gxv[0] + gbuf[tid];
            float gf = gxv[1] + gbuf[tid + 256];
            float gg = gxv[2] + gbuf[tid + 512];
            float go = gxv[3] + gbuf[tid + 768];
            c = sigm(gf) * c + sigm(gi) * ftanh(gg);
            float h = sigm(go) * ftanh(c);
            hbuf[(s + 1) & 1][tid] = (_Float16)h;
            if (!dir) { if (t < NP1) fout[t * HDIM + tid] = h; }
            else      { if (t >= 1)  bout[(t - 1) * HDIM + tid] = h; }
        }
        __syncthreads();
#pragma unroll
        for (int g = 0; g < 4; ++g) gxv[g] = gn[g];
    }
}

// ---------------- K5: D matrices ----------------
__global__ __launch_bounds__(256) void k_dmat(const float* __restrict__ fm, const float* __restrict__ bm,
                                              const float* __restrict__ lw1, const float* __restrict__ sw1,
                                              float* __restrict__ dlab, float* __restrict__ dspl) {
    const int t0 = blockIdx.x * 8;
    const int tid = threadIdx.x;
    __shared__ float fs[8 * HDIM], bs[8 * HDIM];
    for (int idx = tid; idx < 8 * HDIM; idx += 256) {
        int tt = t0 + (idx >> 8);
        float fv = 0.f, bv = 0.f;
        if (tt < NP1) { fv = fm[tt * HDIM + (idx & 255)]; bv = bm[tt * HDIM + (idx & 255)]; }
        fs[idx] = fv; bs[idx] = bv;
    }
    __syncthreads();
    float al[8], asp[8];
#pragma unroll
    for (int q = 0; q < 8; ++q) { al[q] = 0.f; asp[q] = 0.f; }
    const float4* lrow = (const float4*)(lw1 + tid * 512);
    const float4* srow = (const float4*)(sw1 + tid * 512);
    const float4* fs4 = (const float4*)fs;
    const float4* bs4 = (const float4*)bs;
    for (int d4 = 0; d4 < 64; ++d4) {
        float4 wlv = lrow[d4], wsv = srow[d4];
#pragma unroll
        for (int tt = 0; tt < 8; ++tt) {
            float4 e = fs4[tt * 64 + d4];
            al[tt]  += wlv.x * e.x + wlv.y * e.y + wlv.z * e.z + wlv.w * e.w;
            asp[tt] += wsv.x * e.x + wsv.y * e.y + wsv.z * e.z + wsv.w * e.w;
        }
    }
    for (int d4 = 0; d4 < 64; ++d4) {
        float4 wlv = lrow[64 + d4], wsv = srow[64 + d4];
#pragma unroll
        for (int tt = 0; tt < 8; ++tt) {
            float4 e = bs4[tt * 64 + d4];
            al[tt]  -= wlv.x * e.x + wlv.y * e.y + wlv.z * e.z + wlv.w * e.w;
            asp[tt] -= wsv.x * e.x + wsv.y * e.y + wsv.z * e.z + wsv.w * e.w;
        }
    }
    for (int tt = 0; tt < 8; ++tt) {
        int t = t0 + tt;
        if (t < NP1) { dlab[t * HDIM + tid] = al[tt]; dspl[t * HDIM + tid] = asp[tt]; }
    }
}

// ---------------- K6: pack lab_w2 into f16 MFMA B-fragments ----------------
// w2f[kb8][m][j] = (f16) lw2[m][kb8*8+j],  kb8=k>>3, j=k&7
__global__ void k_w2f(const float* __restrict__ lw2, _Float16* __restrict__ w2f) {
    int m = blockIdx.x, k = threadIdx.x;
    w2f[(((k >> 3) * LABV) + m) * 8 + (k & 7)] = (_Float16)lw2[m * HDIM + k];
}

// ---------------- K7: fused output kernel (MFMA f16) ----------------
// block = (jt, i); 256 threads (4 waves); out[i, jt*32 .. +31, 0..128]
// wave w owns m-tiles {2w, 2w+1}; both 16-row j-tiles; K=256 in 8 mfma steps.
__global__ __launch_bounds__(256) void k_out(const float* __restrict__ dlab, const float* __restrict__ dspl,
                                             const float* __restrict__ lb1, const float* __restrict__ sb1,
                                             const _Float16* __restrict__ w2f, const float* __restrict__ lb2,
                                             const float* __restrict__ sw2, const float* __restrict__ sb2,
                                             float* __restrict__ outp) {
    const int i = blockIdx.y, jtblk = blockIdx.x, tid = threadIdx.x;
    __shared__ float dli[HDIM], dsi[HDIM];
    __shared__ _Float16 hl[32 * 264];   // row stride 264 f16 (=33*16B) to spread banks

    dli[tid] = dlab[i * HDIM + tid] - lb1[tid];
    dsi[tid] = dspl[i * HDIM + tid] - sb1[tid];
    __syncthreads();

    // phase 1: hidden activations (f16) for the label MLP
    for (int j = 0; j < 32; ++j) {
        int jj = jtblk * 32 + j;
        float v = 0.f;
        if (jj < NP1) v = fmaxf(dlab[jj * HDIM + tid] - dli[tid], 0.f);
        hl[j * 264 + tid] = (_Float16)v;
    }

    // phase 1.5: split scores
    {
        int w = tid >> 6, l = tid & 63;
        float sw2v[4];
#pragma unroll
        for (int cc = 0; cc < 4; ++cc) sw2v[cc] = sw2[l + 64 * cc];
        float sb2v = sb2[0];
        for (int q = 0; q < 8; ++q) {
            int jj = jtblk * 32 + w * 8 + q;
            if (jj < NP1) {
                float sum = 0.f;
#pragma unroll
                for (int cc = 0; cc < 4; ++cc) {
                    int k = l + 64 * cc;
                    float v = fmaxf(dspl[jj * HDIM + k] - dsi[k], 0.f);
                    sum += v * sw2v[cc];
                }
#pragma unroll
                for (int off = 32; off > 0; off >>= 1) sum += __shfl_down(sum, off, 64);
                if (l == 0) outp[(size_t)(i * NP1 + jj) * OUTC + 128] = sum + sb2v;
            }
        }
    }
    __syncthreads();

    // phase 2: label GEMM via mfma_f32_16x16x32_f16
    const int w = tid >> 6, l = tid & 63;
    const int q = l >> 4, c16 = l & 15;
    f32x4 acc[2][2];
#pragma unroll
    for (int a = 0; a < 2; ++a)
#pragma unroll
        for (int b = 0; b < 2; ++b) acc[a][b] = (f32x4){0.f, 0.f, 0.f, 0.f};

    const int mt0 = w * 2;
#pragma unroll
    for (int kb = 0; kb < 8; ++kb) {
        // A-frags: lane holds hl[jt*16 + c16][kb*32 + q*8 .. +7]
        f16x8 a0 = *(const f16x8*)(hl + (0 * 16 + c16) * 264 + kb * 32 + q * 8);
        f16x8 a1 = *(const f16x8*)(hl + (1 * 16 + c16) * 264 + kb * 32 + q * 8);
        // B-frags: lane holds w2f[kb*4+q][mt*16 + c16][0..7]
        f16x8 b0 = *(const f16x8*)(w2f + (((kb * 4 + q) * LABV) + mt0 * 16 + c16) * 8);
        f16x8 b1 = *(const f16x8*)(w2f + (((kb * 4 + q) * LABV) + (mt0 + 1) * 16 + c16) * 8);
        acc[0][0] = __builtin_amdgcn_mfma_f32_16x16x32_f16(a0, b0, acc[0][0], 0, 0, 0);
        acc[0][1] = __builtin_amdgcn_mfma_f32_16x16x32_f16(a0, b1, acc[0][1], 0, 0, 0);
        acc[1][0] = __builtin_amdgcn_mfma_f32_16x16x32_f16(a1, b0, acc[1][0], 0, 0, 0);
        acc[1][1] = __builtin_amdgcn_mfma_f32_16x16x32_f16(a1, b1, acc[1][1], 0, 0, 0);
    }

    // epilogue: C/D layout col = lane&15, row = q*4 + reg
#pragma unroll
    for (int mb = 0; mb < 2; ++mb) {
        int m = (mt0 + mb) * 16 + c16;
        float bias = lb2[m];
#pragma unroll
        for (int jt = 0; jt < 2; ++jt) {
#pragma unroll
            for (int r = 0; r < 4; ++r) {
                int jj = jtblk * 32 + jt * 16 + q * 4 + r;
                if (jj < NP1) outp[(size_t)(i * NP1 + jj) * OUTC + m] = acc[jt][mb][r] + bias;
            }
        }
    }
}

// ---------------- launcher ----------------
extern "C" void kernel_launch(void* const* d_in, const int* in_sizes, int n_in,
                              void* d_out, int out_size, void* d_ws, size_t ws_size,
                              hipStream_t stream) {
    const int*   tag_ids  = (const int*)d_in[0];
    const int*   word_ids = (const int*)d_in[1];
    const float* tag_emb  = (const float*)d_in[2];
    const float* word_emb = (const float*)d_in[3];
    const float* wxf = (const float*)d_in[4];
    const float* whf = (const float*)d_in[5];
    const float* bf_ = (const float*)d_in[6];
    const float* wxb = (const float*)d_in[7];
    const float* whb = (const float*)d_in[8];
    const float* bb_ = (const float*)d_in[9];
    const float* lw1 = (const float*)d_in[10];
    const float* lb1 = (const float*)d_in[11];
    const float* lw2 = (const float*)d_in[12];
    const float* lb2 = (const float*)d_in[13];
    const float* sw1 = (const float*)d_in[14];
    const float* sb1 = (const float*)d_in[15];
    const float* sw2 = (const float*)d_in[16];
    const float* sb2 = (const float*)d_in[17];

    char* ws = (char*)d_ws;
    float*     emb  = (float*)(ws + OFF_EMB);
    float*     gx   = (float*)(ws + OFF_GX);
    uint4*     wreg = (uint4*)(ws + OFF_WREG);
    uint4*     wldsg= (uint4*)(ws + OFF_WLDS);
    float*     fm   = (float*)(ws + OFF_F);
    float*     bm   = (float*)(ws + OFF_B);
    float*     dlab = (float*)(ws + OFF_DL);
    float*     dspl = (float*)(ws + OFF_DS);
    _Float16*  w2f  = (_Float16*)(ws + OFF_W2F);
    float*     outp = (float*)d_out;

    k_embed<<<dim3(SEQ), dim3(EMBD), 0, stream>>>(tag_ids, word_ids, tag_emb, word_emb, emb);
    k_gx   <<<dim3(49, 2), dim3(256), 0, stream>>>(emb, wxf, bf_, wxb, bb_, gx);
    k_wconv<<<dim3(2, 128), dim3(256), 0, stream>>>(whf, whb, wreg, wldsg);
    k_w2f  <<<dim3(LABV), dim3(HDIM), 0, stream>>>(lw2, w2f);
    k_lstm <<<dim3(2), dim3(512), 0, stream>>>(wreg, wldsg, gx, fm, bm);
    k_dmat <<<dim3(49), dim3(256), 0, stream>>>(fm, bm, lw1, sw1, dlab, dspl);
    k_out  <<<dim3(13, NP1), dim3(256), 0, stream>>>(dlab, dspl, lb1, sb1, w2f, lb2, sw2, sb2, outp);
}

// Round 7
// 1434.884 us; speedup vs baseline: 1.5192x; 1.5192x over previous
//
#include <hip/hip_runtime.h>
#include <cstdint>

// ---------------- problem constants ----------------
#define SEQ   386
#define NP1   385
#define HDIM  256
#define G4    1024
#define EMBD  128
#define LABV  128
#define OUTC  129   // 128 label + 1 split

typedef _Float16 h2 __attribute__((ext_vector_type(2)));
typedef _Float16 f16x8 __attribute__((ext_vector_type(8)));
typedef float    f32x4 __attribute__((ext_vector_type(4)));

__device__ __forceinline__ uint32_t pack2(float a, float b) {
    h2 v; v[0] = (_Float16)a; v[1] = (_Float16)b;
    return __builtin_bit_cast(uint32_t, v);
}

__device__ __forceinline__ float dot2(uint32_t wa, uint32_t hb, float c) {
    h2 a = __builtin_bit_cast(h2, wa);
    h2 b = __builtin_bit_cast(h2, hb);
#if __has_builtin(__builtin_amdgcn_fdot2)
    return __builtin_amdgcn_fdot2(a, b, c, false);
#else
    return fmaf((float)a[1], (float)b[1], fmaf((float)a[0], (float)b[0], c));
#endif
}

__device__ __forceinline__ float sigm(float x) { return 1.f / (1.f + __expf(-x)); }
__device__ __forceinline__ float ftanh(float x) {
    x = fminf(fmaxf(x, -15.f), 15.f);
    float e = __expf(2.f * x);
    return (e - 1.f) / (e + 1.f);
}

// ---------------- workspace layout (bytes) ----------------
#define OFF_EMB   0u                       // 386*128*4        = 197632
#define OFF_GX    197632u                  // 2*386*1024*4     = 3162112
#define OFF_WPK   3359744u                 // 2*2*32*512*16    = 1048576 (per-(dir,half) reg weights)
#define OFF_F     4408320u                 // 385*256*4        = 394240
#define OFF_B     4802560u                 // 385*256*4        = 394240
#define OFF_DL    5196800u                 // 385*256*4        = 394240
#define OFF_DS    5591040u                 // 385*256*4        = 394240
#define OFF_W2F   5985280u                 // 32*128*8*2       = 65536 (f16 B-fragments)
#define OFF_HX    6050816u                 // 2*2*256*2        = 2048  (f16 h exchange, dbuf)
#define OFF_FLG   6052864u                 // 2*2*386*4        = 6176  (step flags)
// total ~6.06 MB

// ---------------- K1: embedding gather ----------------
__global__ void k_embed(const int* __restrict__ tag_ids, const int* __restrict__ word_ids,
                        const float* __restrict__ tag_emb, const float* __restrict__ word_emb,
                        float* __restrict__ emb) {
    int t = blockIdx.x, d = threadIdx.x;
    emb[t * EMBD + d] = tag_emb[tag_ids[t] * EMBD + d] + word_emb[word_ids[t] * EMBD + d];
}

// ---------------- K2: Gx[dir][t][1024] = Wx @ emb[t] + b ----------------
__global__ __launch_bounds__(256) void k_gx(const float* __restrict__ emb,
                                            const float* __restrict__ wxf, const float* __restrict__ bf_,
                                            const float* __restrict__ wxb, const float* __restrict__ bb_,
                                            float* __restrict__ gx) {
    const int dir = blockIdx.y;
    const int t0  = blockIdx.x * 8;
    const float* Wx   = dir ? wxb : wxf;
    const float* bias = dir ? bb_ : bf_;
    __shared__ float se[8 * EMBD];
    for (int idx = threadIdx.x; idx < 8 * EMBD; idx += 256) {
        int tt = t0 + (idx >> 7);
        se[idx] = (tt < SEQ) ? emb[tt * EMBD + (idx & 127)] : 0.f;
    }
    __syncthreads();
    const float4* se4 = (const float4*)se;
    for (int q = 0; q < 4; ++q) {
        int r = threadIdx.x + q * 256;
        float bv = bias[r];
        float acc[8];
#pragma unroll
        for (int tt = 0; tt < 8; ++tt) acc[tt] = bv;
        const float4* wrow = (const float4*)(Wx + r * EMBD);
        for (int d4 = 0; d4 < 32; ++d4) {
            float4 w = wrow[d4];
#pragma unroll
            for (int tt = 0; tt < 8; ++tt) {
                float4 e = se4[tt * 32 + d4];
                acc[tt] += w.x * e.x + w.y * e.y + w.z * e.z + w.w * e.w;
            }
        }
        for (int tt = 0; tt < 8; ++tt) {
            int t = t0 + tt;
            if (t < SEQ) gx[(dir * SEQ + t) * G4 + r] = acc[tt];
        }
    }
}

// ---------------- K3: pack Wh fp32 -> f16 pairs, per-(dir,half) thread layout ----------------
// k_lstm block (dir,half), thread tl (0..511) owns gate row r = (tl>>7)*256 + half*128 + (tl&127),
// all 256 cols as 32 uint4: wpk[((dir*2+half)*32 + c)*512 + tl] = cols 8c..8c+7 of row r.
__global__ void k_wconv(const float* __restrict__ whf, const float* __restrict__ whb,
                        uint4* __restrict__ wpk) {
    const int dir = blockIdx.x;
    const float* Wh = dir ? whb : whf;
    int idx = blockIdx.y * 256 + threadIdx.x;   // [0, 32768)
    int tl = idx & 511;
    int c2 = idx >> 9;                          // 0..63
    int half = c2 >> 5, c = c2 & 31;
    int r = (tl >> 7) * 256 + half * 128 + (tl & 127);
    const float* src = Wh + r * HDIM + c * 8;
    uint4 o;
    o.x = pack2(src[0], src[1]); o.y = pack2(src[2], src[3]);
    o.z = pack2(src[4], src[5]); o.w = pack2(src[6], src[7]);
    wpk[((dir * 2 + half) * 32 + c) * 512 + tl] = o;
}

// ---------------- K3b: zero the step flags (run before every k_lstm) ----------------
__global__ void k_zf(int* __restrict__ flags) {
    int i = blockIdx.x * 256 + threadIdx.x;
    if (i < 2 * 2 * SEQ) flags[i] = 0;
}

// ---------------- K4: the two LSTMs, each split across 2 CUs ----------------
// grid = 4 blocks: b = dir*2 + half. Block owns 512 gate rows (elements
// half*128..half*128+127, all 4 gates). Thread = 1 row x 256 cols = 32 uint4
// = 128 VGPRs of weights + ~30 misc: fits the 256/wave budget with headroom
// (the thing rounds 0-6 never had), so no AGPR shuffling and NO LDS weight
// stream. Per-step h-half exchange between paired blocks via global f16 dbuf
// + step-indexed flags: producer stores + threadfence + atomicAdd (per-wave
// coalesced, G12); consumer wave spins with agent-scope atomic loads
// (bypasses stale L1, G16) CONCURRENTLY with the activation phase. Lockstep
// is mutual (step s+1 needs the partner's flag[s]), so skew is bounded.
__global__ __launch_bounds__(512)
void k_lstm(const uint4* __restrict__ wpk,
            const float* __restrict__ gx,
            _Float16* __restrict__ hx16, int* __restrict__ flags,
            float* __restrict__ fout, float* __restrict__ bout) {
    const int b    = blockIdx.x;
    const int dir  = b >> 1;
    const int half = b & 1;
    const int tid  = threadIdx.x;             // 0..511
    const int q    = tid >> 7;                // gate 0..3 (i,f,g,o)
    const int el   = tid & 127;               // element-local
    const int E    = half * 128 + el;         // global element (tid<128 path)

    __shared__ uint32_t hsh[128];             // full h as 128 f16-pairs
    __shared__ float    gbuf[512];

    // weights: 32 uint4 = 128 VGPRs (row r, cols 0..255)
    uint4 w[32];
    const uint4* wp = wpk + (dir * 2 + half) * 32 * 512;
#pragma unroll
    for (int c = 0; c < 32; ++c) w[c] = wp[c * 512 + tid];

    const int r = q * 256 + half * 128 + el;  // this thread's gate row
    const float* gxd = gx + dir * SEQ * G4;
    uint32_t* hx32 = (uint32_t*)hx16;
    const int fOwn = (dir * 2 + half) * SEQ;
    const int fRem = (dir * 2 + (1 - half)) * SEQ;

    if (tid < 128) hsh[tid] = 0u;
    float c = 0.f;
    const int tfirst = dir ? (SEQ - 1) : 0;
    float gxv = gxd[tfirst * G4 + r];
    float gn;
    __syncthreads();

    for (int s = 0; s < SEQ; ++s) {
        const int t = dir ? (SEQ - 1 - s) : s;
        if (s < SEQ - 1) {
            int tn = dir ? (SEQ - 2 - s) : (s + 1);
            gn = gxd[tn * G4 + r];
        } else gn = 0.f;

        // dots: row r . h (sequential cols, same order as the verified round-0)
        float a = gxv;
        const uint4* h4 = (const uint4*)hsh;
#pragma unroll
        for (int g = 0; g < 32; ++g) {
            uint4 hv = h4[g];
            a = dot2(w[g].x, hv.x, a);
            a = dot2(w[g].y, hv.y, a);
            a = dot2(w[g].z, hv.z, a);
            a = dot2(w[g].w, hv.w, a);
        }
        gbuf[tid] = a;
        __syncthreads();                       // barrier1: gates ready

        if (tid < 128) {
            // activation for element E
            float gi = gbuf[el];
            float gf = gbuf[el + 128];
            float gg = gbuf[el + 256];
            float go = gbuf[el + 384];
            c = sigm(gf) * c + sigm(gi) * ftanh(gg);
            float h = sigm(go) * ftanh(c);
            _Float16 hh = (_Float16)h;
            ((_Float16*)hsh)[E] = hh;                          // local publish
            hx16[dir * 512 + (s & 1) * 256 + E] = hh;          // remote publish
            __threadfence();
            atomicAdd(&flags[fOwn + s], 1);
            if (!dir) { if (t < NP1) fout[t * HDIM + E] = h; }
            else      { if (t >= 1)  bout[(t - 1) * HDIM + E] = h; }
        } else if (tid < 192) {
            // fetch partner's half of h for the NEXT step (concurrent w/ activation)
            int p = tid - 128;                 // 0..63 pair index within remote half
            while (__hip_atomic_load(&flags[fRem + s], __ATOMIC_ACQUIRE,
                                     __HIP_MEMORY_SCOPE_AGENT) < 128) {
                __builtin_amdgcn_s_sleep(1);
            }
            uint32_t v = __hip_atomic_load(
                &hx32[dir * 256 + (s & 1) * 128 + (1 - half) * 64 + p],
                __ATOMIC_RELAXED, __HIP_MEMORY_SCOPE_AGENT);
            hsh[(1 - half) * 64 + p] = v;
        }
        __syncthreads();                       // barrier2: hsh complete for s+1
        gxv = gn;
    }
}

// ---------------- K5: D matrices ----------------
__global__ __launch_bounds__(256) void k_dmat(const float* __restrict__ fm, const float* __restrict__ bm,
                                              const float* __restrict__ lw1, const float* __restrict__ sw1,
                                              float* __restrict__ dlab, float* __restrict__ dspl) {
    const int t0 = blockIdx.x * 8;
    const int tid = threadIdx.x;
    __shared__ float fs[8 * HDIM], bs[8 * HDIM];
    for (int idx = tid; idx < 8 * HDIM; idx += 256) {
        int tt = t0 + (idx >> 8);
        float fv = 0.f, bv = 0.f;
        if (tt < NP1) { fv = fm[tt * HDIM + (idx & 255)]; bv = bm[tt * HDIM + (idx & 255)]; }
        fs[idx] = fv; bs[idx] = bv;
    }
    __syncthreads();
    float al[8], asp[8];
#pragma unroll
    for (int q = 0; q < 8; ++q) { al[q] = 0.f; asp[q] = 0.f; }
    const float4* lrow = (const float4*)(lw1 + tid * 512);
    const float4* srow = (const float4*)(sw1 + tid * 512);
    const float4* fs4 = (const float4*)fs;
    const float4* bs4 = (const float4*)bs;
    for (int d4 = 0; d4 < 64; ++d4) {
        float4 wlv = lrow[d4], wsv = srow[d4];
#pragma unroll
        for (int tt = 0; tt < 8; ++tt) {
            float4 e = fs4[tt * 64 + d4];
            al[tt]  += wlv.x * e.x + wlv.y * e.y + wlv.z * e.z + wlv.w * e.w;
            asp[tt] += wsv.x * e.x + wsv.y * e.y + wsv.z * e.z + wsv.w * e.w;
        }
    }
    for (int d4 = 0; d4 < 64; ++d4) {
        float4 wlv = lrow[64 + d4], wsv = srow[64 + d4];
#pragma unroll
        for (int tt = 0; tt < 8; ++tt) {
            float4 e = bs4[tt * 64 + d4];
            al[tt]  -= wlv.x * e.x + wlv.y * e.y + wlv.z * e.z + wlv.w * e.w;
            asp[tt] -= wsv.x * e.x + wsv.y * e.y + wsv.z * e.z + wsv.w * e.w;
        }
    }
    for (int tt = 0; tt < 8; ++tt) {
        int t = t0 + tt;
        if (t < NP1) { dlab[t * HDIM + tid] = al[tt]; dspl[t * HDIM + tid] = asp[tt]; }
    }
}

// ---------------- K6: pack lab_w2 into f16 MFMA B-fragments ----------------
__global__ void k_w2f(const float* __restrict__ lw2, _Float16* __restrict__ w2f) {
    int m = blockIdx.x, k = threadIdx.x;
    w2f[(((k >> 3) * LABV) + m) * 8 + (k & 7)] = (_Float16)lw2[m * HDIM + k];
}

// ---------------- K7: fused output kernel (MFMA f16) ----------------
__global__ __launch_bounds__(256) void k_out(const float* __restrict__ dlab, const float* __restrict__ dspl,
                                             const float* __restrict__ lb1, const float* __restrict__ sb1,
                                             const _Float16* __restrict__ w2f, const float* __restrict__ lb2,
                                             const float* __restrict__ sw2, const float* __restrict__ sb2,
                                             float* __restrict__ outp) {
    const int i = blockIdx.y, jtblk = blockIdx.x, tid = threadIdx.x;
    __shared__ float dli[HDIM], dsi[HDIM];
    __shared__ _Float16 hl[32 * 264];   // row stride 264 f16 (=33*16B) to spread banks

    dli[tid] = dlab[i * HDIM + tid] - lb1[tid];
    dsi[tid] = dspl[i * HDIM + tid] - sb1[tid];
    __syncthreads();

    // phase 1: hidden activations (f16) for the label MLP
    for (int j = 0; j < 32; ++j) {
        int jj = jtblk * 32 + j;
        float v = 0.f;
        if (jj < NP1) v = fmaxf(dlab[jj * HDIM + tid] - dli[tid], 0.f);
        hl[j * 264 + tid] = (_Float16)v;
    }

    // phase 1.5: split scores
    {
        int w = tid >> 6, l = tid & 63;
        float sw2v[4];
#pragma unroll
        for (int cc = 0; cc < 4; ++cc) sw2v[cc] = sw2[l + 64 * cc];
        float sb2v = sb2[0];
        for (int q = 0; q < 8; ++q) {
            int jj = jtblk * 32 + w * 8 + q;
            if (jj < NP1) {
                float sum = 0.f;
#pragma unroll
                for (int cc = 0; cc < 4; ++cc) {
                    int k = l + 64 * cc;
                    float v = fmaxf(dspl[jj * HDIM + k] - dsi[k], 0.f);
                    sum += v * sw2v[cc];
                }
#pragma unroll
                for (int off = 32; off > 0; off >>= 1) sum += __shfl_down(sum, off, 64);
                if (l == 0) outp[(size_t)(i * NP1 + jj) * OUTC + 128] = sum + sb2v;
            }
        }
    }
    __syncthreads();

    // phase 2: label GEMM via mfma_f32_16x16x32_f16
    const int w = tid >> 6, l = tid & 63;
    const int q = l >> 4, c16 = l & 15;
    f32x4 acc[2][2];
#pragma unroll
    for (int a = 0; a < 2; ++a)
#pragma unroll
        for (int b = 0; b < 2; ++b) acc[a][b] = (f32x4){0.f, 0.f, 0.f, 0.f};

    const int mt0 = w * 2;
#pragma unroll
    for (int kb = 0; kb < 8; ++kb) {
        f16x8 a0 = *(const f16x8*)(hl + (0 * 16 + c16) * 264 + kb * 32 + q * 8);
        f16x8 a1 = *(const f16x8*)(hl + (1 * 16 + c16) * 264 + kb * 32 + q * 8);
        f16x8 b0 = *(const f16x8*)(w2f + (((kb * 4 + q) * LABV) + mt0 * 16 + c16) * 8);
        f16x8 b1 = *(const f16x8*)(w2f + (((kb * 4 + q) * LABV) + (mt0 + 1) * 16 + c16) * 8);
        acc[0][0] = __builtin_amdgcn_mfma_f32_16x16x32_f16(a0, b0, acc[0][0], 0, 0, 0);
        acc[0][1] = __builtin_amdgcn_mfma_f32_16x16x32_f16(a0, b1, acc[0][1], 0, 0, 0);
        acc[1][0] = __builtin_amdgcn_mfma_f32_16x16x32_f16(a1, b0, acc[1][0], 0, 0, 0);
        acc[1][1] = __builtin_amdgcn_mfma_f32_16x16x32_f16(a1, b1, acc[1][1], 0, 0, 0);
    }

#pragma unroll
    for (int mb = 0; mb < 2; ++mb) {
        int m = (mt0 + mb) * 16 + c16;
        float bias = lb2[m];
#pragma unroll
        for (int jt = 0; jt < 2; ++jt) {
#pragma unroll
            for (int r = 0; r < 4; ++r) {
                int jj = jtblk * 32 + jt * 16 + q * 4 + r;
                if (jj < NP1) outp[(size_t)(i * NP1 + jj) * OUTC + m] = acc[jt][mb][r] + bias;
            }
        }
    }
}

// ---------------- launcher ----------------
extern "C" void kernel_launch(void* const* d_in, const int* in_sizes, int n_in,
                              void* d_out, int out_size, void* d_ws, size_t ws_size,
                              hipStream_t stream) {
    const int*   tag_ids  = (const int*)d_in[0];
    const int*   word_ids = (const int*)d_in[1];
    const float* tag_emb  = (const float*)d_in[2];
    const float* word_emb = (const float*)d_in[3];
    const float* wxf = (const float*)d_in[4];
    const float* whf = (const float*)d_in[5];
    const float* bf_ = (const float*)d_in[6];
    const float* wxb = (const float*)d_in[7];
    const float* whb = (const float*)d_in[8];
    const float* bb_ = (const float*)d_in[9];
    const float* lw1 = (const float*)d_in[10];
    const float* lb1 = (const float*)d_in[11];
    const float* lw2 = (const float*)d_in[12];
    const float* lb2 = (const float*)d_in[13];
    const float* sw1 = (const float*)d_in[14];
    const float* sb1 = (const float*)d_in[15];
    const float* sw2 = (const float*)d_in[16];
    const float* sb2 = (const float*)d_in[17];

    char* ws = (char*)d_ws;
    float*     emb  = (float*)(ws + OFF_EMB);
    float*     gx   = (float*)(ws + OFF_GX);
    uint4*     wpk  = (uint4*)(ws + OFF_WPK);
    float*     fm   = (float*)(ws + OFF_F);
    float*     bm   = (float*)(ws + OFF_B);
    float*     dlab = (float*)(ws + OFF_DL);
    float*     dspl = (float*)(ws + OFF_DS);
    _Float16*  w2f  = (_Float16*)(ws + OFF_W2F);
    _Float16*  hx16 = (_Float16*)(ws + OFF_HX);
    int*       flg  = (int*)(ws + OFF_FLG);
    float*     outp = (float*)d_out;

    k_embed<<<dim3(SEQ), dim3(EMBD), 0, stream>>>(tag_ids, word_ids, tag_emb, word_emb, emb);
    k_gx   <<<dim3(49, 2), dim3(256), 0, stream>>>(emb, wxf, bf_, wxb, bb_, gx);
    k_wconv<<<dim3(2, 128), dim3(256), 0, stream>>>(whf, whb, wpk);
    k_w2f  <<<dim3(LABV), dim3(HDIM), 0, stream>>>(lw2, w2f);
    k_zf   <<<dim3(7), dim3(256), 0, stream>>>(flg);
    k_lstm <<<dim3(4), dim3(512), 0, stream>>>(wpk, gx, hx16, flg, fm, bm);
    k_dmat <<<dim3(49), dim3(256), 0, stream>>>(fm, bm, lw1, sw1, dlab, dspl);
    k_out  <<<dim3(13, NP1), dim3(256), 0, stream>>>(dlab, dspl, lb1, sb1, w2f, lb2, sw2, sb2, outp);
}